// Round 6
// baseline (305.281 us; speedup 1.0000x reference)
//
#include <hip/hip_runtime.h>
#include <stdint.h>

// CRF loss: S=32768, L=512. Chunked forward algorithm, exp-domain, fp8 MFMA.
// CH=8 -> 4096 fwd chunks + 4095 bwd chunks, 16 chunks (MFMA columns) per WG
// -> 256 fwd WGs + 256 bwd WGs = 512 WGs = 2 WGs/CU (TLP hides the per-step
// serial chain; round 3 at 1 WG/CU stalled 55% of cycles).
// E' = 2*exp(T) as fp8 e4m3 MFMA A-fragments in VGPRs (<=128 VGPR for 4 w/SIMD).
// Per step: C[512x16] = E' x P (v_mfma_f32_16x16x32_fp8_fp8), *exp(feat),
// per-column max renorm -> fp8 P' in LDS (B-fragment layout).
// m accumulates log(M) - ln448 - ln2 (-ln2 compensates E'=2E).
// Lessons: r4 dynamic-indexed prefetch -> scratch spill; r5 asm-barrier ->
// conservative vmcnt(0) drains. Both reverted: plain __syncthreads, loads
// issued at step top (address early, use after MFMA), no prefetch regs.
// Tail fused: pair tickets (fwd b + bwd b own chunks 16b..16b+16 exactly)
// + final ticket last-WG reduction. 2 kernels total.

#define S_LEN 32768
#define L 512
#define CH 8
#define NCF 4096            // fwd chunks (c = 0..4095)
#define WGF 256
#define WGB 256
#define NWG 512
#define LN448 6.104793232f
#define LN2   0.6931471806f

// ws layout (bytes), ~8.7 MB
#define OFF_EAF  0                       // 256 KB A-frag fp8 E'  (fwd)
#define OFF_EAB  (256*1024)              // 256 KB A-frag fp8 E'^T (bwd)
#define OFF_G    (512*1024)              // 4096*512 bf16 (4 MB)
#define OFF_H    (OFF_G + NCF*L*2)       // 4096*512 bf16 (4 MB, row 0 unused)
#define OFF_LSE  (OFF_H + NCF*L*2)       // [c]=lse(h+g), [NCF+c]=lse(h), [2*NCF]=lse(g_last)
#define OFF_PART (OFF_LSE + (2*NCF+4)*4) // 512 f32 gold partials
#define OFF_PTKT (OFF_PART + NWG*4)      // 256 u32 pair tickets
#define OFF_FTKT (OFF_PTKT + WGF*4)      // 1 u32 final ticket

typedef float v4f __attribute__((ext_vector_type(4)));

__device__ __forceinline__ float b2f(unsigned short u){
  return __uint_as_float(((unsigned)u) << 16);
}
__device__ __forceinline__ unsigned short f2b(float x){
  unsigned u = __float_as_uint(x);
  return (unsigned short)((u + 0x7fffu + ((u >> 16) & 1u)) >> 16);
}
__device__ __forceinline__ unsigned char to_fp8(float v){
  int u = __builtin_amdgcn_cvt_pk_fp8_f32(v, v, 0, false);
  return (unsigned char)(u & 0xff);
}

// ---------- prep: A-fragment-swizzled fp8 E'/E'^T + ticket zeroing ----------
// long index = ((w*4+mt)*16+kt)*64 + lane ; byte r of that long =
//   Mat[m = w*64+mt*16+(lane&15)][k = kt*32+(lane>>4)*8+r]
extern "C" __global__ void crf_prep(const float* __restrict__ T,
                                    unsigned char* __restrict__ EAf,
                                    unsigned char* __restrict__ EAb,
                                    unsigned int* __restrict__ ptkt,
                                    unsigned int* __restrict__ ftkt){
  int tid = blockIdx.x*512 + threadIdx.x;        // 0..262143
  if (tid < WGF + 1) { if (tid < WGF) ptkt[tid] = 0u; else *ftkt = 0u; }
  int r    = tid & 7;
  int lane = (tid >> 3) & 63;
  int kt   = (tid >> 9) & 15;
  int mtw  = tid >> 13;                          // w*4+mt, 0..31
  int j = (mtw >> 2)*64 + (mtw & 3)*16 + (lane & 15);
  int i = kt*32 + ((lane >> 4) << 3) + r;
  EAf[tid] = to_fp8(2.0f * __expf(T[j*L + i]));  // E'[j][i]
  EAb[tid] = to_fp8(2.0f * __expf(T[i*L + j]));  // E'^T[j][i]
}

// ---------- block sum over 512 threads ----------
__device__ __forceinline__ float blockSum(float v, float* sred){
  #pragma unroll
  for (int off = 32; off >= 1; off >>= 1) v += __shfl_xor(v, off);
  int wid = threadIdx.x >> 6, lane = threadIdx.x & 63;
  if (lane == 0) sred[wid] = v;
  __syncthreads();
  if (threadIdx.x < 8) {
    float t = sred[threadIdx.x];
    t += __shfl_xor(t, 4); t += __shfl_xor(t, 2); t += __shfl_xor(t, 1);
    if (threadIdx.x == 0) sred[15] = t;
  }
  __syncthreads();
  float r = sred[15];
  __syncthreads();
  return r;
}

// ---------- main kernel: chunks + fused tail ----------
extern "C" __global__ __launch_bounds__(512, 4)
void crf_chunks(const float* __restrict__ logit,
                const unsigned char* __restrict__ EAf,
                const unsigned char* __restrict__ EAb,
                unsigned short* __restrict__ G, unsigned short* __restrict__ H,
                const int* __restrict__ labels, const float* __restrict__ T,
                float* __restrict__ part, float* __restrict__ lsebuf,
                unsigned int* __restrict__ ptkt, unsigned int* __restrict__ ftkt,
                float* __restrict__ out){
  // P in MFMA-B-fragment order: byte(n=col,k=row) =
  //   (k>>5)*512 + (((k>>3)&3)*16 + n)*8 + (k&7)
  __shared__ __align__(16) unsigned char Pl[2][8192];
  __shared__ float sPart[16][8];
  __shared__ float sred[16];
  __shared__ unsigned sOld, sOld2;

  const int tid  = threadIdx.x;
  const int w    = tid >> 6;
  const int lane = tid & 63;
  const int quad = lane >> 4;
  const int cl   = lane & 15;                    // MFMA column = chunk slot
  const bool fwd = (blockIdx.x < WGF);
  const int  b   = fwd ? blockIdx.x : (blockIdx.x - WGF);
  const int  cg  = fwd ? (b*16 + cl) : (1 + b*16 + cl);
  const int  cgc = min(cg, NCF-1);
  const bool isc0 = fwd && (cg == 0);
  const int  jrow0 = w*64 + quad*4;              // C-layout base row (+mt*16)

  // ---- E fragments in registers ----
  const long* EA = (const long*)(fwd ? EAf : EAb);
  long eA[4][16];
  #pragma unroll
  for (int mt = 0; mt < 4; ++mt)
    #pragma unroll
    for (int kt = 0; kt < 16; ++kt)
      eA[mt][kt] = EA[(((w<<2)+mt)<<4 | kt)*64 + lane];

  // ---- init v ----
  float vr[4][4];
  if (fwd) {
    #pragma unroll
    for (int mt = 0; mt < 4; ++mt)
      #pragma unroll
      for (int r = 0; r < 4; ++r) vr[mt][r] = 1.0f;
  } else {
    const float* lp = logit + (size_t)(cgc*CH + CH - 1)*L + jrow0;
    #pragma unroll
    for (int mt = 0; mt < 4; ++mt) {
      float4 x = *(const float4*)(lp + mt*16);
      vr[mt][0] = __expf(x.x); vr[mt][1] = __expf(x.y);
      vr[mt][2] = __expf(x.z); vr[mt][3] = __expf(x.w);
    }
  }
  float m = 0.0f;

  auto renorm_store = [&](int dst){
    float mx = vr[0][0];
    #pragma unroll
    for (int mt = 0; mt < 4; ++mt)
      #pragma unroll
      for (int r = 0; r < 4; ++r) mx = fmaxf(mx, vr[mt][r]);
    mx = fmaxf(mx, __shfl_xor(mx, 16));
    mx = fmaxf(mx, __shfl_xor(mx, 32));          // column max within wave
    if (quad == 0) sPart[cl][w] = mx;
    __syncthreads();
    float4 pa = *(const float4*)&sPart[cl][0];
    float4 pb = *(const float4*)&sPart[cl][4];
    float M = fmaxf(fmaxf(fmaxf(pa.x,pa.y),fmaxf(pa.z,pa.w)),
                    fmaxf(fmaxf(pb.x,pb.y),fmaxf(pb.z,pb.w)));
    float sc = 448.0f / M;
    #pragma unroll
    for (int mt = 0; mt < 4; ++mt) {
      int u = __builtin_amdgcn_cvt_pk_fp8_f32(vr[mt][0]*sc, vr[mt][1]*sc, 0, false);
      u     = __builtin_amdgcn_cvt_pk_fp8_f32(vr[mt][2]*sc, vr[mt][3]*sc, u, true);
      int r0 = jrow0 + mt*16;
      *(int*)&Pl[dst][(r0 >> 5)*512 + ((((r0 >> 3) & 3)*16 + cl) << 3) + (r0 & 7)] = u;
    }
    m += __logf(M) - LN448;
    __syncthreads();
  };

  auto step = [&](int k, int rdBuf, int wrBuf){
    const bool last = (k == CH-1);
    const bool useF = fwd || !last;

    // issue feature-row loads early (consumed after the MFMA block)
    float4 x0, x1, x2, x3;
    if (useF) {
      const int t = fwd ? (cgc*CH + k) : (cgc*CH + CH - 2 - k);
      const float* lp = logit + (size_t)t*L + jrow0;
      x0 = *(const float4*)(lp);      x1 = *(const float4*)(lp + 16);
      x2 = *(const float4*)(lp + 32); x3 = *(const float4*)(lp + 48);
    }

    v4f acc[4];
    #pragma unroll
    for (int mt = 0; mt < 4; ++mt) acc[mt] = (v4f){0.f,0.f,0.f,0.f};
    #pragma unroll
    for (int kt = 0; kt < 16; ++kt) {
      long bb = *(const long*)&Pl[rdBuf][kt*512 + lane*8];
      #pragma unroll
      for (int mt = 0; mt < 4; ++mt)
        acc[mt] = __builtin_amdgcn_mfma_f32_16x16x32_fp8_fp8(eA[mt][kt], bb, acc[mt], 0, 0, 0);
    }
    m -= LN2;                                    // compensate E' = 2E

    if (useF) {
      float4 xs[4] = {x0, x1, x2, x3};
      #pragma unroll
      for (int mt = 0; mt < 4; ++mt) {
        float f0 = __expf(xs[mt].x), f1 = __expf(xs[mt].y);
        float f2 = __expf(xs[mt].z), f3 = __expf(xs[mt].w);
        vr[mt][0] = acc[mt][0]*f0; vr[mt][1] = acc[mt][1]*f1;
        vr[mt][2] = acc[mt][2]*f2; vr[mt][3] = acc[mt][3]*f3;
        if (k == 0 && isc0) {                    // exact anchor: alpha_0
          vr[mt][0] = f0; vr[mt][1] = f1; vr[mt][2] = f2; vr[mt][3] = f3;
        }
      }
      if (k == 0 && isc0) m = 0.0f;
    } else {
      #pragma unroll
      for (int mt = 0; mt < 4; ++mt)
        #pragma unroll
        for (int r = 0; r < 4; ++r) vr[mt][r] = acc[mt][r];
    }

    if (last) {
      if (cg <= NCF-1) {
        unsigned short* dst = (fwd ? G : H) + (size_t)cg*L + jrow0;
        #pragma unroll
        for (int mt = 0; mt < 4; ++mt) {
          ushort4 o;
          o.x = f2b(__logf(vr[mt][0]) + m); o.y = f2b(__logf(vr[mt][1]) + m);
          o.z = f2b(__logf(vr[mt][2]) + m); o.w = f2b(__logf(vr[mt][3]) + m);
          *(ushort4*)(dst + mt*16) = o;
        }
      }
    } else {
      renorm_store(wrBuf);
    }
  };

  renorm_store(0);
  #pragma unroll
  for (int kk = 0; kk < CH; kk += 2) {   // parity static: even reads 0, odd reads 1
    step(kk,     0, 1);
    step(kk + 1, 1, 0);
  }

  // ---- gold partial: 64 timesteps per WG ----
  {
    float gv = 0.f;
    if (tid < 64) {
      int t = blockIdx.x*64 + tid;
      int yt = labels[t];
      gv = logit[(size_t)t*L + yt];
      if (t > 0) gv += T[yt*L + labels[t-1]];
    }
    float s = blockSum(gv, sred);
    if (tid == 0) part[blockIdx.x] = s;
  }

  // ---- pair rendezvous: second arriver computes lse for chunks 16b+1..16b+16 ----
  __syncthreads();                               // drain all prior stores
  if (tid == 0) { __threadfence(); sOld = atomicAdd(&ptkt[b], 1u); }
  __syncthreads();
  if (sOld == 1u) {
    __threadfence();                             // acquire partner's G/H
    #pragma unroll
    for (int q = 0; q < 2; ++q) {
      int idx = w*2 + q;                         // 0..15
      int c = b*16 + 1 + idx;                    // 1..4096
      if (c <= NCF-1) {
        const ushort4* hp = (const ushort4*)(H + (size_t)c*L + lane*8);
        const ushort4* gp = (const ushort4*)(G + (size_t)(c-1)*L + lane*8);
        ushort4 h0 = hp[0], h1 = hp[1], g0 = gp[0], g1 = gp[1];
        float hh[8] = {b2f(h0.x),b2f(h0.y),b2f(h0.z),b2f(h0.w),
                       b2f(h1.x),b2f(h1.y),b2f(h1.z),b2f(h1.w)};
        float aa[8] = {hh[0]+b2f(g0.x),hh[1]+b2f(g0.y),hh[2]+b2f(g0.z),hh[3]+b2f(g0.w),
                       hh[4]+b2f(g1.x),hh[5]+b2f(g1.y),hh[6]+b2f(g1.z),hh[7]+b2f(g1.w)};
        float Ma = aa[0], Mh = hh[0];
        #pragma unroll
        for (int r = 1; r < 8; ++r) { Ma = fmaxf(Ma, aa[r]); Mh = fmaxf(Mh, hh[r]); }
        #pragma unroll
        for (int off = 1; off <= 32; off <<= 1) {
          Ma = fmaxf(Ma, __shfl_xor(Ma, off));
          Mh = fmaxf(Mh, __shfl_xor(Mh, off));
        }
        float sa = 0.f, sh = 0.f;
        #pragma unroll
        for (int r = 0; r < 8; ++r) { sa += __expf(aa[r]-Ma); sh += __expf(hh[r]-Mh); }
        #pragma unroll
        for (int off = 1; off <= 32; off <<= 1) {
          sa += __shfl_xor(sa, off);
          sh += __shfl_xor(sh, off);
        }
        if (lane == 0) { lsebuf[c] = Ma + __logf(sa); lsebuf[NCF + c] = Mh + __logf(sh); }
      } else {                                   // b==WGF-1,idx==15: lse(g_last)
        const ushort4* gp = (const ushort4*)(G + (size_t)(NCF-1)*L + lane*8);
        ushort4 u0 = gp[0], u1 = gp[1];
        float v[8] = {b2f(u0.x),b2f(u0.y),b2f(u0.z),b2f(u0.w),
                      b2f(u1.x),b2f(u1.y),b2f(u1.z),b2f(u1.w)};
        float M = v[0];
        #pragma unroll
        for (int r = 1; r < 8; ++r) M = fmaxf(M, v[r]);
        #pragma unroll
        for (int off = 1; off <= 32; off <<= 1) M = fmaxf(M, __shfl_xor(M, off));
        float s = 0.f;
        #pragma unroll
        for (int r = 0; r < 8; ++r) s += __expf(v[r] - M);
        #pragma unroll
        for (int off = 1; off <= 32; off <<= 1) s += __shfl_xor(s, off);
        if (lane == 0) lsebuf[2*NCF] = M + __logf(s);
      }
    }
  }

  // ---- final ticket: 512th WG reduces everything ----
  __syncthreads();                               // drain lse stores
  if (tid == 0) { __threadfence(); sOld2 = atomicAdd(ftkt, 1u); }
  __syncthreads();
  if (sOld2 == (unsigned)(NWG - 1)) {
    __threadfence();
    float acc = 0.f;
    for (int c = tid; c < NCF; c += 512)
      if (c >= 1) acc += lsebuf[c] - lsebuf[NCF + c];
    acc -= part[tid];
    float s = blockSum(acc, sred);
    if (tid == 0) out[0] = lsebuf[2*NCF] + s;
  }
}

extern "C" void kernel_launch(void* const* d_in, const int* in_sizes, int n_in,
                              void* d_out, int out_size, void* d_ws, size_t ws_size,
                              hipStream_t stream){
  const float* logit = (const float*)d_in[0];
  const int* labels  = (const int*)d_in[1];
  const float* T     = (const float*)d_in[2];
  float* out = (float*)d_out;
  char* ws = (char*)d_ws;
  unsigned char* EAf = (unsigned char*)(ws + OFF_EAF);
  unsigned char* EAb = (unsigned char*)(ws + OFF_EAB);
  unsigned short* G  = (unsigned short*)(ws + OFF_G);
  unsigned short* H  = (unsigned short*)(ws + OFF_H);
  float* lsebuf = (float*)(ws + OFF_LSE);
  float* part   = (float*)(ws + OFF_PART);
  unsigned int* ptkt = (unsigned int*)(ws + OFF_PTKT);
  unsigned int* ftkt = (unsigned int*)(ws + OFF_FTKT);

  crf_prep  <<<512, 512, 0, stream>>>(T, EAf, EAb, ptkt, ftkt);
  crf_chunks<<<NWG, 512, 0, stream>>>(logit, EAf, EAb, G, H, labels, T,
                                      part, lsebuf, ptkt, ftkt, out);
}

// Round 7
// 168.460 us; speedup vs baseline: 1.8122x; 1.8122x over previous
//
#include <hip/hip_runtime.h>
#include <stdint.h>

// CRF loss: S=32768, L=512. Chunked forward algorithm, exp-domain, fp8 MFMA.
// CH=16 -> 2048 fwd + 2047 bwd chunks, 16 chunks (MFMA cols) per WG ->
// 128 fwd + 128 bwd WGs = 256 WGs (1/CU; E-in-regs caps occupancy at 1 WG/CU:
// ~228 combined VGPR+AGPR -> r6's launch_bounds(512,4) cap spilled E, 230us).
// Per step: C[512x16] = E' x P (v_mfma 16x16x32 fp8), *exp(feat), renorm,
// fp8 P' -> LDS (B-frag layout). STALE-SCALE renorm: pack with sc=448/(8*Mprev)
// where Mprev = prev step's wave maxima (exchanged via the one step barrier,
// sMax double-buffered with P). m logs the APPLIED scale -> exact bookkeeping;
// fminf clamp guards the e^+-2 growth band (G=8). Step 0 + seed exact.
// One barrier/step (was 2): barrier separates step k's P/sMax writes from
// step k+1's reads; reads/writes of one step touch different buffers.
// m accumulates log(scale) - ln448 - ln2 (-ln2 compensates E'=2E).
// Tail fused: pair tickets + final ticket (r5, non-blocking => dispatch-safe).

#define S_LEN 32768
#define L 512
#define CH 16
#define NCF 2048
#define WGF 128
#define WGB 128
#define NWG 256
#define LN448 6.104793232f
#define LN2   0.6931471806f

// ws layout (bytes), ~4.73 MB
#define OFF_EAF  0                       // 256 KB A-frag fp8 E'  (fwd)
#define OFF_EAB  (256*1024)              // 256 KB A-frag fp8 E'^T (bwd)
#define OFF_G    (512*1024)              // 2048*512 bf16
#define OFF_H    (OFF_G + NCF*L*2)       // 2048*512 bf16 (row 0 unused)
#define OFF_LSE  (OFF_H + NCF*L*2)       // [c]=lse(h+g), [NCF+c]=lse(h), [2NCF]=lse(g_last)
#define OFF_PART (OFF_LSE + (2*NCF+4)*4) // 256 f32 gold partials
#define OFF_PTKT (OFF_PART + NWG*4)      // 128 u32 pair tickets
#define OFF_FTKT (OFF_PTKT + WGF*4)      // 1 u32 final ticket

typedef float v4f __attribute__((ext_vector_type(4)));

__device__ __forceinline__ float b2f(unsigned short u){
  return __uint_as_float(((unsigned)u) << 16);
}
__device__ __forceinline__ unsigned short f2b(float x){
  unsigned u = __float_as_uint(x);
  return (unsigned short)((u + 0x7fffu + ((u >> 16) & 1u)) >> 16);
}
__device__ __forceinline__ unsigned char to_fp8(float v){
  int u = __builtin_amdgcn_cvt_pk_fp8_f32(v, v, 0, false);
  return (unsigned char)(u & 0xff);
}

// ---------- prep: A-fragment-swizzled fp8 E'/E'^T + ticket zeroing ----------
extern "C" __global__ void crf_prep(const float* __restrict__ T,
                                    unsigned char* __restrict__ EAf,
                                    unsigned char* __restrict__ EAb,
                                    unsigned int* __restrict__ ptkt,
                                    unsigned int* __restrict__ ftkt){
  int tid = blockIdx.x*512 + threadIdx.x;        // 0..262143
  if (tid < WGF + 1) { if (tid < WGF) ptkt[tid] = 0u; else *ftkt = 0u; }
  int r    = tid & 7;
  int lane = (tid >> 3) & 63;
  int kt   = (tid >> 9) & 15;
  int mtw  = tid >> 13;                          // w*4+mt, 0..31
  int j = (mtw >> 2)*64 + (mtw & 3)*16 + (lane & 15);
  int i = kt*32 + ((lane >> 4) << 3) + r;
  EAf[tid] = to_fp8(2.0f * __expf(T[j*L + i]));  // E'[j][i]
  EAb[tid] = to_fp8(2.0f * __expf(T[i*L + j]));  // E'^T[j][i]
}

// ---------- block sum over 512 threads ----------
__device__ __forceinline__ float blockSum(float v, float* sred){
  #pragma unroll
  for (int off = 32; off >= 1; off >>= 1) v += __shfl_xor(v, off);
  int wid = threadIdx.x >> 6, lane = threadIdx.x & 63;
  if (lane == 0) sred[wid] = v;
  __syncthreads();
  if (threadIdx.x < 8) {
    float t = sred[threadIdx.x];
    t += __shfl_xor(t, 4); t += __shfl_xor(t, 2); t += __shfl_xor(t, 1);
    if (threadIdx.x == 0) sred[15] = t;
  }
  __syncthreads();
  float r = sred[15];
  __syncthreads();
  return r;
}

// ---------- main kernel ----------
extern "C" __global__ __launch_bounds__(512, 2)
void crf_chunks(const float* __restrict__ logit,
                const unsigned char* __restrict__ EAf,
                const unsigned char* __restrict__ EAb,
                unsigned short* __restrict__ G, unsigned short* __restrict__ H,
                const int* __restrict__ labels, const float* __restrict__ T,
                float* __restrict__ part, float* __restrict__ lsebuf,
                unsigned int* __restrict__ ptkt, unsigned int* __restrict__ ftkt,
                float* __restrict__ out){
  // P in MFMA-B-fragment order: byte(n=col,k=row) =
  //   (k>>5)*512 + (((k>>3)&3)*16 + n)*8 + (k&7)
  __shared__ __align__(16) unsigned char Pl[2][8192];
  __shared__ __align__(16) float sMax[2][16][8];
  __shared__ float sred[16];
  __shared__ unsigned sOld, sOld2;

  const int tid  = threadIdx.x;
  const int w    = tid >> 6;
  const int lane = tid & 63;
  const int quad = lane >> 4;
  const int cl   = lane & 15;                    // MFMA column = chunk slot
  const bool fwd = (blockIdx.x < WGF);
  const int  b   = fwd ? blockIdx.x : (blockIdx.x - WGF);
  const int  cg  = fwd ? (b*16 + cl) : (1 + b*16 + cl);
  const int  cgc = min(cg, NCF-1);
  const bool isc0 = fwd && (cg == 0);
  const int  jrow0 = w*64 + quad*4;              // C-layout base row (+mt*16)

  // ---- E fragments in registers ----
  const long* EA = (const long*)(fwd ? EAf : EAb);
  long eA[4][16];
  #pragma unroll
  for (int mt = 0; mt < 4; ++mt)
    #pragma unroll
    for (int kt = 0; kt < 16; ++kt)
      eA[mt][kt] = EA[(((w<<2)+mt)<<4 | kt)*64 + lane];

  float vr[4][4];
  float m = 0.0f;

  auto wave_max = [&]()->float{
    float mx = vr[0][0];
    #pragma unroll
    for (int mt = 0; mt < 4; ++mt)
      #pragma unroll
      for (int r = 0; r < 4; ++r) mx = fmaxf(mx, vr[mt][r]);
    mx = fmaxf(mx, __shfl_xor(mx, 16));
    mx = fmaxf(mx, __shfl_xor(mx, 32));          // column max within wave
    return mx;
  };
  auto max8 = [&](int buf)->float{
    float4 pa = *(const float4*)&sMax[buf][cl][0];
    float4 pb = *(const float4*)&sMax[buf][cl][4];
    return fmaxf(fmaxf(fmaxf(pa.x,pa.y),fmaxf(pa.z,pa.w)),
                 fmaxf(fmaxf(pb.x,pb.y),fmaxf(pb.z,pb.w)));
  };
  auto pack_store = [&](int dst, float sc){
    #pragma unroll
    for (int mt = 0; mt < 4; ++mt) {
      float p0 = fminf(vr[mt][0]*sc, 448.f), p1 = fminf(vr[mt][1]*sc, 448.f);
      float p2 = fminf(vr[mt][2]*sc, 448.f), p3 = fminf(vr[mt][3]*sc, 448.f);
      int u = __builtin_amdgcn_cvt_pk_fp8_f32(p0, p1, 0, false);
      u     = __builtin_amdgcn_cvt_pk_fp8_f32(p2, p3, u, true);
      int r0 = jrow0 + mt*16;
      *(int*)&Pl[dst][(r0 >> 5)*512 + ((((r0 >> 3) & 3)*16 + cl) << 3) + (r0 & 7)] = u;
    }
  };
  auto mfma_block = [&](int rdBuf, v4f (&acc)[4]){
    #pragma unroll
    for (int mt = 0; mt < 4; ++mt) acc[mt] = (v4f){0.f,0.f,0.f,0.f};
    #pragma unroll
    for (int kt = 0; kt < 16; ++kt) {
      long bb = *(const long*)&Pl[rdBuf][kt*512 + lane*8];
      #pragma unroll
      for (int mt = 0; mt < 4; ++mt)
        acc[mt] = __builtin_amdgcn_mfma_f32_16x16x32_fp8_fp8(eA[mt][kt], bb, acc[mt], 0, 0, 0);
    }
  };

  // ---- seed (exact, 2 barriers) -> P[0], sMax[0] (unused by step 0) ----
  if (fwd) {
    #pragma unroll
    for (int mt = 0; mt < 4; ++mt)
      #pragma unroll
      for (int r = 0; r < 4; ++r) vr[mt][r] = 1.0f;
  } else {
    const float* lp = logit + (size_t)(cgc*CH + CH - 1)*L + jrow0;
    #pragma unroll
    for (int mt = 0; mt < 4; ++mt) {
      float4 x = *(const float4*)(lp + mt*16);
      vr[mt][0] = __expf(x.x); vr[mt][1] = __expf(x.y);
      vr[mt][2] = __expf(x.z); vr[mt][3] = __expf(x.w);
    }
  }
  {
    float mx = wave_max();
    if (quad == 0) sMax[0][cl][w] = mx;
    __syncthreads();
    float M = max8(0);
    pack_store(0, 448.f / M);
    m += __logf(M) - LN448;
    __syncthreads();
  }

  // ---- step 0 (exact, 2 barriers): reads P[0], writes P[1]+sMax[1] ----
  {
    const int t = fwd ? (cgc*CH) : (cgc*CH + CH - 2);
    const float* lp = logit + (size_t)t*L + jrow0;
    float4 x0 = *(const float4*)(lp);      float4 x1 = *(const float4*)(lp + 16);
    float4 x2 = *(const float4*)(lp + 32); float4 x3 = *(const float4*)(lp + 48);
    v4f acc[4];
    mfma_block(0, acc);
    m -= LN2;
    float4 xs[4] = {x0, x1, x2, x3};
    #pragma unroll
    for (int mt = 0; mt < 4; ++mt) {
      float f0 = __expf(xs[mt].x), f1 = __expf(xs[mt].y);
      float f2 = __expf(xs[mt].z), f3 = __expf(xs[mt].w);
      vr[mt][0] = acc[mt][0]*f0; vr[mt][1] = acc[mt][1]*f1;
      vr[mt][2] = acc[mt][2]*f2; vr[mt][3] = acc[mt][3]*f3;
      if (isc0) { vr[mt][0] = f0; vr[mt][1] = f1; vr[mt][2] = f2; vr[mt][3] = f3; }
    }
    if (isc0) m = 0.0f;
    float mx = wave_max();
    if (quad == 0) sMax[1][cl][w] = mx;
    __syncthreads();
    float M = max8(1);
    pack_store(1, 448.f / M);
    m += __logf(M) - LN448;
    __syncthreads();
  }

  // ---- steps 1..CH-2: stale-scale, ONE barrier each ----
  for (int k = 1; k <= CH-2; ++k) {
    const int in = k & 1, outb = in ^ 1;
    // early logit load (consumed after MFMA)
    const int t = fwd ? (cgc*CH + k) : (cgc*CH + CH - 2 - k);
    const float* lp = logit + (size_t)t*L + jrow0;
    float4 x0 = *(const float4*)(lp);      float4 x1 = *(const float4*)(lp + 16);
    float4 x2 = *(const float4*)(lp + 32); float4 x3 = *(const float4*)(lp + 48);
    // stale scale from previous step's maxima (overlaps MFMA)
    float M8 = 8.0f * max8(in);
    float sc = 448.f / M8;

    v4f acc[4];
    mfma_block(in, acc);

    float4 xs[4] = {x0, x1, x2, x3};
    #pragma unroll
    for (int mt = 0; mt < 4; ++mt) {
      float f0 = __expf(xs[mt].x), f1 = __expf(xs[mt].y);
      float f2 = __expf(xs[mt].z), f3 = __expf(xs[mt].w);
      vr[mt][0] = acc[mt][0]*f0; vr[mt][1] = acc[mt][1]*f1;
      vr[mt][2] = acc[mt][2]*f2; vr[mt][3] = acc[mt][3]*f3;
    }
    float mx = wave_max();
    if (quad == 0) sMax[outb][cl][w] = mx;
    pack_store(outb, sc);
    m += __logf(M8) - LN448 - LN2;
    __syncthreads();
  }

  // ---- last step (k = CH-1): reads P[(CH-1)&1], writes G/H ----
  {
    const int k = CH-1;
    const int in = k & 1;
    float4 x0, x1, x2, x3;
    if (fwd) {
      const float* lp = logit + (size_t)(cgc*CH + k)*L + jrow0;
      x0 = *(const float4*)(lp);      x1 = *(const float4*)(lp + 16);
      x2 = *(const float4*)(lp + 32); x3 = *(const float4*)(lp + 48);
    }
    v4f acc[4];
    mfma_block(in, acc);
    m -= LN2;
    if (fwd) {
      float4 xs[4] = {x0, x1, x2, x3};
      #pragma unroll
      for (int mt = 0; mt < 4; ++mt) {
        float f0 = __expf(xs[mt].x), f1 = __expf(xs[mt].y);
        float f2 = __expf(xs[mt].z), f3 = __expf(xs[mt].w);
        vr[mt][0] = acc[mt][0]*f0; vr[mt][1] = acc[mt][1]*f1;
        vr[mt][2] = acc[mt][2]*f2; vr[mt][3] = acc[mt][3]*f3;
      }
    } else {
      #pragma unroll
      for (int mt = 0; mt < 4; ++mt)
        #pragma unroll
        for (int r = 0; r < 4; ++r) vr[mt][r] = acc[mt][r];
    }
    if (cg <= NCF-1) {
      unsigned short* dst = (fwd ? G : H) + (size_t)cg*L + jrow0;
      #pragma unroll
      for (int mt = 0; mt < 4; ++mt) {
        ushort4 o;
        o.x = f2b(__logf(vr[mt][0]) + m); o.y = f2b(__logf(vr[mt][1]) + m);
        o.z = f2b(__logf(vr[mt][2]) + m); o.w = f2b(__logf(vr[mt][3]) + m);
        *(ushort4*)(dst + mt*16) = o;
      }
    }
  }

  // ---- gold partial: 128 timesteps per WG ----
  {
    float gv = 0.f;
    if (tid < 128) {
      int t = blockIdx.x*128 + tid;
      int yt = labels[t];
      gv = logit[(size_t)t*L + yt];
      if (t > 0) gv += T[yt*L + labels[t-1]];
    }
    float s = blockSum(gv, sred);
    if (tid == 0) part[blockIdx.x] = s;
  }

  // ---- pair rendezvous: second arriver computes lse for chunks 16b+1..16b+16 ----
  __syncthreads();
  if (tid == 0) { __threadfence(); sOld = atomicAdd(&ptkt[b], 1u); }
  __syncthreads();
  if (sOld == 1u) {
    __threadfence();
    #pragma unroll
    for (int q = 0; q < 2; ++q) {
      int idx = w*2 + q;                         // 0..15
      int c = b*16 + 1 + idx;                    // 1..2048
      if (c <= NCF-1) {
        const ushort4* hp = (const ushort4*)(H + (size_t)c*L + lane*8);
        const ushort4* gp = (const ushort4*)(G + (size_t)(c-1)*L + lane*8);
        ushort4 h0 = hp[0], h1 = hp[1], g0 = gp[0], g1 = gp[1];
        float hh[8] = {b2f(h0.x),b2f(h0.y),b2f(h0.z),b2f(h0.w),
                       b2f(h1.x),b2f(h1.y),b2f(h1.z),b2f(h1.w)};
        float aa[8] = {hh[0]+b2f(g0.x),hh[1]+b2f(g0.y),hh[2]+b2f(g0.z),hh[3]+b2f(g0.w),
                       hh[4]+b2f(g1.x),hh[5]+b2f(g1.y),hh[6]+b2f(g1.z),hh[7]+b2f(g1.w)};
        float Ma = aa[0], Mh = hh[0];
        #pragma unroll
        for (int r = 1; r < 8; ++r) { Ma = fmaxf(Ma, aa[r]); Mh = fmaxf(Mh, hh[r]); }
        #pragma unroll
        for (int off = 1; off <= 32; off <<= 1) {
          Ma = fmaxf(Ma, __shfl_xor(Ma, off));
          Mh = fmaxf(Mh, __shfl_xor(Mh, off));
        }
        float sa = 0.f, sh = 0.f;
        #pragma unroll
        for (int r = 0; r < 8; ++r) { sa += __expf(aa[r]-Ma); sh += __expf(hh[r]-Mh); }
        #pragma unroll
        for (int off = 1; off <= 32; off <<= 1) {
          sa += __shfl_xor(sa, off);
          sh += __shfl_xor(sh, off);
        }
        if (lane == 0) { lsebuf[c] = Ma + __logf(sa); lsebuf[NCF + c] = Mh + __logf(sh); }
      } else {                                   // b==127,idx==15: lse(g_last)
        const ushort4* gp = (const ushort4*)(G + (size_t)(NCF-1)*L + lane*8);
        ushort4 u0 = gp[0], u1 = gp[1];
        float v[8] = {b2f(u0.x),b2f(u0.y),b2f(u0.z),b2f(u0.w),
                      b2f(u1.x),b2f(u1.y),b2f(u1.z),b2f(u1.w)};
        float M = v[0];
        #pragma unroll
        for (int r = 1; r < 8; ++r) M = fmaxf(M, v[r]);
        #pragma unroll
        for (int off = 1; off <= 32; off <<= 1) M = fmaxf(M, __shfl_xor(M, off));
        float s = 0.f;
        #pragma unroll
        for (int r = 0; r < 8; ++r) s += __expf(v[r] - M);
        #pragma unroll
        for (int off = 1; off <= 32; off <<= 1) s += __shfl_xor(s, off);
        if (lane == 0) lsebuf[2*NCF] = M + __logf(s);
      }
    }
  }

  // ---- final ticket: 256th WG reduces everything ----
  __syncthreads();
  if (tid == 0) { __threadfence(); sOld2 = atomicAdd(ftkt, 1u); }
  __syncthreads();
  if (sOld2 == (unsigned)(NWG - 1)) {
    __threadfence();
    float acc = 0.f;
    for (int c = tid; c < NCF; c += 512)
      if (c >= 1) acc += lsebuf[c] - lsebuf[NCF + c];
    if (tid < NWG) acc -= part[tid];
    float s = blockSum(acc, sred);
    if (tid == 0) out[0] = lsebuf[2*NCF] + s;
  }
}

extern "C" void kernel_launch(void* const* d_in, const int* in_sizes, int n_in,
                              void* d_out, int out_size, void* d_ws, size_t ws_size,
                              hipStream_t stream){
  const float* logit = (const float*)d_in[0];
  const int* labels  = (const int*)d_in[1];
  const float* T     = (const float*)d_in[2];
  float* out = (float*)d_out;
  char* ws = (char*)d_ws;
  unsigned char* EAf = (unsigned char*)(ws + OFF_EAF);
  unsigned char* EAb = (unsigned char*)(ws + OFF_EAB);
  unsigned short* G  = (unsigned short*)(ws + OFF_G);
  unsigned short* H  = (unsigned short*)(ws + OFF_H);
  float* lsebuf = (float*)(ws + OFF_LSE);
  float* part   = (float*)(ws + OFF_PART);
  unsigned int* ptkt = (unsigned int*)(ws + OFF_PTKT);
  unsigned int* ftkt = (unsigned int*)(ws + OFF_FTKT);

  crf_prep  <<<512, 512, 0, stream>>>(T, EAf, EAb, ptkt, ftkt);
  crf_chunks<<<NWG, 512, 0, stream>>>(logit, EAf, EAb, G, H, labels, T,
                                      part, lsebuf, ptkt, ftkt, out);
}